// Round 1
// baseline (881.423 us; speedup 1.0000x reference)
//
#include <hip/hip_runtime.h>
#include <hip/hip_bf16.h>

// Problem constants
#define T_ 4096
#define H_ 1024
#define E_ 16
#define I_ 768
#define EI_ 12288   // E_*I_
#define KTOP 8

typedef __attribute__((ext_vector_type(8))) short bf16x8;
typedef __attribute__((ext_vector_type(4))) float f32x4;

__device__ __forceinline__ unsigned short f2bf(float f) {
  unsigned u = __builtin_bit_cast(unsigned, f);
  u += 0x7fff + ((u >> 16) & 1);   // round-to-nearest-even
  return (unsigned short)(u >> 16);
}

typedef __attribute__((address_space(3))) void lds_void;
typedef __attribute__((address_space(1))) void g_void;

__device__ __forceinline__ void gload_lds16(const void* g, void* l) {
  __builtin_amdgcn_global_load_lds((g_void*)g, (lds_void*)l, 16, 0, 0);
}

// ---------------- Router: logits -> softmax -> top8 -> renorm ----------------
// one wave (64 threads) per token; lane = e*? : e = lane&15, chunk = lane>>4
__global__ void router_kernel(const float* __restrict__ x,
                              const float* __restrict__ gate_w,
                              float* __restrict__ dense_w) {
  int t = blockIdx.x;
  int lane = threadIdx.x;
  int e = lane & 15;
  int chunk = lane >> 4;
  const float* xr = x + (size_t)t * H_;
  int h0 = chunk * 256;
  float partial = 0.f;
  for (int i = 0; i < 256; i += 4) {
    float4 xv = *reinterpret_cast<const float4*>(xr + h0 + i);
    partial += xv.x * gate_w[(size_t)(h0 + i    ) * E_ + e];
    partial += xv.y * gate_w[(size_t)(h0 + i + 1) * E_ + e];
    partial += xv.z * gate_w[(size_t)(h0 + i + 2) * E_ + e];
    partial += xv.w * gate_w[(size_t)(h0 + i + 3) * E_ + e];
  }
  // reduce over the 4 chunks (lanes differing in bits 4..5)
  partial += __shfl_xor(partial, 16);
  partial += __shfl_xor(partial, 32);
  float logit = partial;
  // max over the 16 experts (bits 0..3)
  float m = logit;
  for (int d = 1; d < 16; d <<= 1) m = fmaxf(m, __shfl_xor(m, d));
  float p = __expf(logit - m);
  // rank of this expert among 16 (desc value, asc index tiebreak)
  int base = lane & ~15;
  int rank = 0;
  for (int j = 0; j < 16; ++j) {
    float pj = __shfl(p, base + j);
    rank += (pj > p) || (pj == p && j < e);
  }
  bool sel = rank < KTOP;
  float contrib = sel ? p : 0.f;
  float s = contrib;
  for (int d = 1; d < 16; d <<= 1) s += __shfl_xor(s, d);
  float w = sel ? p / s : 0.f;
  if (lane < 16) dense_w[(size_t)t * E_ + lane] = w;
}

// ---------------- Cast x (f32 -> bf16), 4 elems/thread ----------------
__global__ void cast_x_kernel(const float* __restrict__ x,
                              unsigned short* __restrict__ xb) {
  int idx = blockIdx.x * blockDim.x + threadIdx.x;
  float4 v = reinterpret_cast<const float4*>(x)[idx];
  ushort4 o;
  o.x = f2bf(v.x); o.y = f2bf(v.y); o.z = f2bf(v.z); o.w = f2bf(v.w);
  *reinterpret_cast<ushort4*>(xb + (size_t)idx * 4) = o;
}

// ---------------- Transpose+cast w1/w3: [E][H][I] f32 -> [E][I][H] bf16 -----
// grid (I_/64, H_/64, 32): z<16 -> w1, else w3 (e = z&15); 256 threads
__global__ void transpose_w13_kernel(const float* __restrict__ w1,
                                     const float* __restrict__ w3,
                                     unsigned short* __restrict__ w1t,
                                     unsigned short* __restrict__ w3t) {
  __shared__ float tile[64][65];
  int i0 = blockIdx.x * 64;
  int h0 = blockIdx.y * 64;
  int e = blockIdx.z & 15;
  const float* src = (blockIdx.z < 16 ? w1 : w3) + (size_t)e * H_ * I_;
  unsigned short* dst = (blockIdx.z < 16 ? w1t : w3t) + (size_t)e * I_ * H_;
  int tx = threadIdx.x & 63, ty = threadIdx.x >> 6;
  for (int r = 0; r < 64; r += 4)
    tile[ty + r][tx] = src[(size_t)(h0 + ty + r) * I_ + i0 + tx];
  __syncthreads();
  for (int r = 0; r < 64; r += 4) {
    int i = ty + r;
    dst[(size_t)(i0 + i) * H_ + h0 + tx] = f2bf(tile[tx][i]);
  }
}

// ---------------- Transpose+cast w2: [E][I][H] f32 -> [H][E*I] bf16 ---------
// grid (H_/64, I_/64, E_); 256 threads
__global__ void transpose_w2_kernel(const float* __restrict__ w2,
                                    unsigned short* __restrict__ w2t) {
  __shared__ float tile[64][65];
  int h0 = blockIdx.x * 64;
  int i0 = blockIdx.y * 64;
  int e = blockIdx.z;
  const float* src = w2 + (size_t)e * I_ * H_;
  int tx = threadIdx.x & 63, ty = threadIdx.x >> 6;
  for (int r = 0; r < 64; r += 4)
    tile[ty + r][tx] = src[(size_t)(i0 + ty + r) * H_ + h0 + tx];
  __syncthreads();
  for (int r = 0; r < 64; r += 4) {
    int h = ty + r;
    w2t[(size_t)(h0 + h) * EI_ + (size_t)e * I_ + i0 + tx] = f2bf(tile[tx][h]);
  }
}

// ---------------- Up/gate GEMM + SwiGLU + route-scale -----------------------
// per expert e: act[t][e*I+i] = silu(x@w1[e]) * (x@w3[e]) * dense_w[t][e]
// 128x128 tile, BK=32, 4 waves (2x2), 16x16x32 bf16 MFMA, dual accumulators.
__global__ __launch_bounds__(256) void moe_up_kernel(
    const unsigned short* __restrict__ xb,    // [T][H] bf16
    const unsigned short* __restrict__ w1t,   // [E][I][H] bf16
    const unsigned short* __restrict__ w3t,   // [E][I][H] bf16
    const float* __restrict__ dense_w,        // [T][E]
    unsigned short* __restrict__ act) {       // [T][E*I] bf16
  __shared__ __align__(16) unsigned short Asm[128 * 32];
  __shared__ __align__(16) unsigned short B1sm[128 * 32];
  __shared__ __align__(16) unsigned short B3sm[128 * 32];
  __shared__ float rw_sm[128];

  const int e = blockIdx.z;
  const int row0 = blockIdx.x * 128;
  const int col0 = blockIdx.y * 128;
  const int tid = threadIdx.x;
  const int lane = tid & 63;
  const int w = tid >> 6;
  const int wm = w >> 1, wn = w & 1;

  if (tid < 128) rw_sm[tid] = dense_w[(size_t)(row0 + tid) * E_ + e];

  // staging: [128][32] bf16 tile = 8KB = 8 chunks of 1KB (64 lanes x 16B)
  const int r_in_chunk = lane >> 2;        // 16 rows per chunk
  const int kpart = (lane & 3) * 8;        // 4 x 8 bf16 per row

  const unsigned short* Abase  = xb  + (size_t)row0 * H_;
  const unsigned short* B1base = w1t + ((size_t)e * I_ + col0) * H_;
  const unsigned short* B3base = w3t + ((size_t)e * I_ + col0) * H_;

  f32x4 acc1[4][4] = {};
  f32x4 acc2[4][4] = {};

  const int lrow = lane & 15;
  const int lk = (lane >> 4) * 8;

  for (int k0 = 0; k0 < H_; k0 += 32) {
    for (int i = 0; i < 2; ++i) {
      int c = w * 2 + i;
      int row = c * 16 + r_in_chunk;
      gload_lds16(Abase  + (size_t)row * H_ + k0 + kpart, &Asm[c * 512]);
      gload_lds16(B1base + (size_t)row * H_ + k0 + kpart, &B1sm[c * 512]);
      gload_lds16(B3base + (size_t)row * H_ + k0 + kpart, &B3sm[c * 512]);
    }
    __syncthreads();  // drains vmcnt before barrier
    bf16x8 af[4], b1f[4], b3f[4];
    for (int m = 0; m < 4; ++m)
      af[m] = *reinterpret_cast<const bf16x8*>(&Asm[(wm * 64 + m * 16 + lrow) * 32 + lk]);
    for (int n = 0; n < 4; ++n) {
      b1f[n] = *reinterpret_cast<const bf16x8*>(&B1sm[(wn * 64 + n * 16 + lrow) * 32 + lk]);
      b3f[n] = *reinterpret_cast<const bf16x8*>(&B3sm[(wn * 64 + n * 16 + lrow) * 32 + lk]);
    }
    for (int m = 0; m < 4; ++m)
      for (int n = 0; n < 4; ++n) {
        acc1[m][n] = __builtin_amdgcn_mfma_f32_16x16x32_bf16(af[m], b1f[n], acc1[m][n], 0, 0, 0);
        acc2[m][n] = __builtin_amdgcn_mfma_f32_16x16x32_bf16(af[m], b3f[n], acc2[m][n], 0, 0, 0);
      }
    __syncthreads();
  }

  // epilogue: C[m][n]: row = (lane>>4)*4 + reg, col = lane&15
  const int crow = (lane >> 4) * 4;
  const int ccol = lane & 15;
  for (int m = 0; m < 4; ++m)
    for (int n = 0; n < 4; ++n)
      for (int r = 0; r < 4; ++r) {
        int rl = wm * 64 + m * 16 + crow + r;
        int cl = wn * 64 + n * 16 + ccol;
        float hv = acc1[m][n][r];
        float uv = acc2[m][n][r];
        float a = (hv / (1.f + __expf(-hv))) * uv * rw_sm[rl];
        act[(size_t)(row0 + rl) * EI_ + (size_t)e * I_ + col0 + cl] = f2bf(a);
      }
}

// ---------------- Down GEMM: out = act @ w2 (K = E*I = 12288) ---------------
__global__ __launch_bounds__(256) void moe_down_kernel(
    const unsigned short* __restrict__ act,  // [T][EI] bf16
    const unsigned short* __restrict__ w2t,  // [H][EI] bf16 (B^T)
    float* __restrict__ out) {               // [T][H] f32
  __shared__ __align__(16) unsigned short Asm[128 * 32];
  __shared__ __align__(16) unsigned short Bsm[128 * 32];

  const int row0 = blockIdx.x * 128;
  const int col0 = blockIdx.y * 128;
  const int tid = threadIdx.x;
  const int lane = tid & 63;
  const int w = tid >> 6;
  const int wm = w >> 1, wn = w & 1;

  const int r_in_chunk = lane >> 2;
  const int kpart = (lane & 3) * 8;

  const unsigned short* Abase = act + (size_t)row0 * EI_;
  const unsigned short* Bbase = w2t + (size_t)col0 * EI_;

  f32x4 acc[4][4] = {};

  const int lrow = lane & 15;
  const int lk = (lane >> 4) * 8;

  for (int k0 = 0; k0 < EI_; k0 += 32) {
    for (int i = 0; i < 2; ++i) {
      int c = w * 2 + i;
      int row = c * 16 + r_in_chunk;
      gload_lds16(Abase + (size_t)row * EI_ + k0 + kpart, &Asm[c * 512]);
      gload_lds16(Bbase + (size_t)row * EI_ + k0 + kpart, &Bsm[c * 512]);
    }
    __syncthreads();
    bf16x8 af[4], bf[4];
    for (int m = 0; m < 4; ++m)
      af[m] = *reinterpret_cast<const bf16x8*>(&Asm[(wm * 64 + m * 16 + lrow) * 32 + lk]);
    for (int n = 0; n < 4; ++n)
      bf[n] = *reinterpret_cast<const bf16x8*>(&Bsm[(wn * 64 + n * 16 + lrow) * 32 + lk]);
    for (int m = 0; m < 4; ++m)
      for (int n = 0; n < 4; ++n)
        acc[m][n] = __builtin_amdgcn_mfma_f32_16x16x32_bf16(af[m], bf[n], acc[m][n], 0, 0, 0);
    __syncthreads();
  }

  const int crow = (lane >> 4) * 4;
  const int ccol = lane & 15;
  for (int m = 0; m < 4; ++m)
    for (int n = 0; n < 4; ++n)
      for (int r = 0; r < 4; ++r) {
        int rl = wm * 64 + m * 16 + crow + r;
        int cl = wn * 64 + n * 16 + ccol;
        out[(size_t)(row0 + rl) * H_ + col0 + cl] = acc[m][n][r];
      }
}

extern "C" void kernel_launch(void* const* d_in, const int* in_sizes, int n_in,
                              void* d_out, int out_size, void* d_ws, size_t ws_size,
                              hipStream_t stream) {
  const float* x      = (const float*)d_in[0];
  const float* gate_w = (const float*)d_in[1];
  const float* w1     = (const float*)d_in[2];
  const float* w3     = (const float*)d_in[3];
  const float* w2     = (const float*)d_in[4];
  float* out = (float*)d_out;

  // workspace layout (all 16B-aligned); total ~176.3 MB
  char* ws = (char*)d_ws;
  float* dense_w      = (float*)ws;                               // T*E*4      = 256KB
  unsigned short* xb  = (unsigned short*)(ws + 262144);           // T*H*2      = 8MB
  unsigned short* w1t = xb  + (size_t)T_ * H_;                    // E*I*H*2    = 24MB
  unsigned short* w3t = w1t + (size_t)E_ * I_ * H_;               // 24MB
  unsigned short* w2t = w3t + (size_t)E_ * I_ * H_;               // H*EI*2     = 24MB
  unsigned short* act = w2t + (size_t)H_ * EI_;                   // T*EI*2     = 96MB

  router_kernel<<<T_, 64, 0, stream>>>(x, gate_w, dense_w);
  cast_x_kernel<<<(T_ * H_ / 4) / 256, 256, 0, stream>>>(x, xb);
  transpose_w13_kernel<<<dim3(I_ / 64, H_ / 64, 32), 256, 0, stream>>>(w1, w3, w1t, w3t);
  transpose_w2_kernel<<<dim3(H_ / 64, I_ / 64, E_), 256, 0, stream>>>(w2, w2t);
  moe_up_kernel<<<dim3(T_ / 128, I_ / 128, E_), 256, 0, stream>>>(xb, w1t, w3t, dense_w, act);
  moe_down_kernel<<<dim3(T_ / 128, H_ / 128), 256, 0, stream>>>(act, w2t, out);
}

// Round 2
// 733.758 us; speedup vs baseline: 1.2012x; 1.2012x over previous
//
#include <hip/hip_runtime.h>
#include <hip/hip_bf16.h>

// Problem constants
#define T_ 4096
#define H_ 1024
#define E_ 16
#define I_ 768
#define EI_ 12288   // E_*I_
#define KTOP 8
#define KSPLIT 3
#define KLEN 4096   // EI_/KSPLIT

typedef __attribute__((ext_vector_type(8))) short bf16x8;
typedef __attribute__((ext_vector_type(4))) float f32x4;

__device__ __forceinline__ unsigned short f2bf(float f) {
  unsigned u = __builtin_bit_cast(unsigned, f);
  u += 0x7fff + ((u >> 16) & 1);   // round-to-nearest-even
  return (unsigned short)(u >> 16);
}

typedef __attribute__((address_space(3))) void lds_void;
typedef __attribute__((address_space(1))) void g_void;

__device__ __forceinline__ void gload_lds16(const void* g, void* l) {
  __builtin_amdgcn_global_load_lds((g_void*)g, (lds_void*)l, 16, 0, 0);
}

// ---------------- Router: logits -> softmax -> top8 -> renorm ----------------
__global__ void router_kernel(const float* __restrict__ x,
                              const float* __restrict__ gate_w,
                              float* __restrict__ dense_w) {
  int t = blockIdx.x;
  int lane = threadIdx.x;
  int e = lane & 15;
  int chunk = lane >> 4;
  const float* xr = x + (size_t)t * H_;
  int h0 = chunk * 256;
  float partial = 0.f;
  for (int i = 0; i < 256; i += 4) {
    float4 xv = *reinterpret_cast<const float4*>(xr + h0 + i);
    partial += xv.x * gate_w[(size_t)(h0 + i    ) * E_ + e];
    partial += xv.y * gate_w[(size_t)(h0 + i + 1) * E_ + e];
    partial += xv.z * gate_w[(size_t)(h0 + i + 2) * E_ + e];
    partial += xv.w * gate_w[(size_t)(h0 + i + 3) * E_ + e];
  }
  partial += __shfl_xor(partial, 16);
  partial += __shfl_xor(partial, 32);
  float logit = partial;
  float m = logit;
  for (int d = 1; d < 16; d <<= 1) m = fmaxf(m, __shfl_xor(m, d));
  float p = __expf(logit - m);
  int base = lane & ~15;
  int rank = 0;
  for (int j = 0; j < 16; ++j) {
    float pj = __shfl(p, base + j);
    rank += (pj > p) || (pj == p && j < e);
  }
  bool sel = rank < KTOP;
  float contrib = sel ? p : 0.f;
  float s = contrib;
  for (int d = 1; d < 16; d <<= 1) s += __shfl_xor(s, d);
  float w = sel ? p / s : 0.f;
  if (lane < 16) dense_w[(size_t)t * E_ + lane] = w;
}

// ---------------- Cast x (f32 -> bf16), 4 elems/thread ----------------
__global__ void cast_x_kernel(const float* __restrict__ x,
                              unsigned short* __restrict__ xb) {
  int idx = blockIdx.x * blockDim.x + threadIdx.x;
  float4 v = reinterpret_cast<const float4*>(x)[idx];
  ushort4 o;
  o.x = f2bf(v.x); o.y = f2bf(v.y); o.z = f2bf(v.z); o.w = f2bf(v.w);
  *reinterpret_cast<ushort4*>(xb + (size_t)idx * 4) = o;
}

// ---------------- Transpose+cast w1/w3: [E][H][I] f32 -> [E][I][H] bf16 -----
__global__ void transpose_w13_kernel(const float* __restrict__ w1,
                                     const float* __restrict__ w3,
                                     unsigned short* __restrict__ w1t,
                                     unsigned short* __restrict__ w3t) {
  __shared__ float tile[64][65];
  int i0 = blockIdx.x * 64;
  int h0 = blockIdx.y * 64;
  int e = blockIdx.z & 15;
  const float* src = (blockIdx.z < 16 ? w1 : w3) + (size_t)e * H_ * I_;
  unsigned short* dst = (blockIdx.z < 16 ? w1t : w3t) + (size_t)e * I_ * H_;
  int tx = threadIdx.x & 63, ty = threadIdx.x >> 6;
  for (int r = 0; r < 64; r += 4)
    tile[ty + r][tx] = src[(size_t)(h0 + ty + r) * I_ + i0 + tx];
  __syncthreads();
  for (int r = 0; r < 64; r += 4) {
    int i = ty + r;
    dst[(size_t)(i0 + i) * H_ + h0 + tx] = f2bf(tile[tx][i]);
  }
}

// ---------------- Transpose+cast w2: [E][I][H] f32 -> [H][E*I] bf16 ---------
__global__ void transpose_w2_kernel(const float* __restrict__ w2,
                                    unsigned short* __restrict__ w2t) {
  __shared__ float tile[64][65];
  int h0 = blockIdx.x * 64;
  int i0 = blockIdx.y * 64;
  int e = blockIdx.z;
  const float* src = w2 + (size_t)e * I_ * H_;
  int tx = threadIdx.x & 63, ty = threadIdx.x >> 6;
  for (int r = 0; r < 64; r += 4)
    tile[ty + r][tx] = src[(size_t)(i0 + ty + r) * H_ + h0 + tx];
  __syncthreads();
  for (int r = 0; r < 64; r += 4) {
    int h = ty + r;
    w2t[(size_t)(h0 + h) * EI_ + (size_t)e * I_ + i0 + tx] = f2bf(tile[tx][h]);
  }
}

// ---------------- Up/gate GEMM + SwiGLU + route-scale -----------------------
// 128x64 block tile, BK=32, 4 waves (2x2), per-wave 64x32 dual accumulator.
// acc = 16 f32x4 (64 regs) + frags 32 regs -> ~3 waves/SIMD occupancy.
__global__ __launch_bounds__(256) void moe_up_kernel(
    const unsigned short* __restrict__ xb,    // [T][H] bf16
    const unsigned short* __restrict__ w1t,   // [E][I][H] bf16
    const unsigned short* __restrict__ w3t,   // [E][I][H] bf16
    const float* __restrict__ dense_w,        // [T][E]
    unsigned short* __restrict__ act) {       // [T][E*I] bf16
  __shared__ __align__(16) unsigned short Asm[128 * 32];   // 8KB
  __shared__ __align__(16) unsigned short B1sm[64 * 32];   // 4KB
  __shared__ __align__(16) unsigned short B3sm[64 * 32];   // 4KB
  __shared__ float rw_sm[128];

  const int e = blockIdx.z;
  const int row0 = blockIdx.x * 128;
  const int col0 = blockIdx.y * 64;
  const int tid = threadIdx.x;
  const int lane = tid & 63;
  const int w = tid >> 6;
  const int wm = w >> 1, wn = w & 1;

  if (tid < 128) rw_sm[tid] = dense_w[(size_t)(row0 + tid) * E_ + e];

  // staging: 16 chunks of 1KB (64 lanes x 16B); wave w owns chunks 4w..4w+3
  const int r_in_chunk = lane >> 2;        // 16 rows per chunk
  const int kpart = (lane & 3) * 8;        // 4 x 8 bf16 per row

  const unsigned short* Abase  = xb  + (size_t)row0 * H_;
  const unsigned short* B1base = w1t + ((size_t)e * I_ + col0) * H_;
  const unsigned short* B3base = w3t + ((size_t)e * I_ + col0) * H_;

  f32x4 acc1[4][2] = {};
  f32x4 acc2[4][2] = {};

  const int lrow = lane & 15;
  const int lk = (lane >> 4) * 8;

  for (int k0 = 0; k0 < H_; k0 += 32) {
    for (int i = 0; i < 4; ++i) {
      int c = w * 4 + i;                      // 0..15, wave-uniform
      if (c < 8) {
        int row = c * 16 + r_in_chunk;        // A rows 0..127
        gload_lds16(Abase + (size_t)row * H_ + k0 + kpart, &Asm[c * 512]);
      } else if (c < 12) {
        int row = (c - 8) * 16 + r_in_chunk;  // B1 rows 0..63
        gload_lds16(B1base + (size_t)row * H_ + k0 + kpart, &B1sm[(c - 8) * 512]);
      } else {
        int row = (c - 12) * 16 + r_in_chunk; // B3 rows 0..63
        gload_lds16(B3base + (size_t)row * H_ + k0 + kpart, &B3sm[(c - 12) * 512]);
      }
    }
    __syncthreads();  // drains vmcnt before barrier
    bf16x8 af[4], b1f[2], b3f[2];
    for (int m = 0; m < 4; ++m)
      af[m] = *reinterpret_cast<const bf16x8*>(&Asm[(wm * 64 + m * 16 + lrow) * 32 + lk]);
    for (int n = 0; n < 2; ++n) {
      b1f[n] = *reinterpret_cast<const bf16x8*>(&B1sm[(wn * 32 + n * 16 + lrow) * 32 + lk]);
      b3f[n] = *reinterpret_cast<const bf16x8*>(&B3sm[(wn * 32 + n * 16 + lrow) * 32 + lk]);
    }
    for (int m = 0; m < 4; ++m)
      for (int n = 0; n < 2; ++n) {
        acc1[m][n] = __builtin_amdgcn_mfma_f32_16x16x32_bf16(af[m], b1f[n], acc1[m][n], 0, 0, 0);
        acc2[m][n] = __builtin_amdgcn_mfma_f32_16x16x32_bf16(af[m], b3f[n], acc2[m][n], 0, 0, 0);
      }
    __syncthreads();
  }

  // epilogue: C[m][n]: row = (lane>>4)*4 + reg, col = lane&15
  const int crow = (lane >> 4) * 4;
  const int ccol = lane & 15;
  for (int m = 0; m < 4; ++m)
    for (int n = 0; n < 2; ++n)
      for (int r = 0; r < 4; ++r) {
        int rl = wm * 64 + m * 16 + crow + r;
        int cl = wn * 32 + n * 16 + ccol;
        float hv = acc1[m][n][r];
        float uv = acc2[m][n][r];
        float a = (hv / (1.f + __expf(-hv))) * uv * rw_sm[rl];
        act[(size_t)(row0 + rl) * EI_ + (size_t)e * I_ + col0 + cl] = f2bf(a);
      }
}

// ---------------- Down GEMM: dout[s] = act @ w2 over K-slice s --------------
// 128x128 tile, BK=32, split-K x3 -> 768 blocks for occupancy/overlap.
__global__ __launch_bounds__(256) void moe_down_kernel(
    const unsigned short* __restrict__ act,  // [T][EI] bf16
    const unsigned short* __restrict__ w2t,  // [H][EI] bf16 (B^T)
    float* __restrict__ dout) {              // [KSPLIT][T][H] f32
  __shared__ __align__(16) unsigned short Asm[128 * 32];
  __shared__ __align__(16) unsigned short Bsm[128 * 32];

  const int row0 = blockIdx.x * 128;
  const int col0 = blockIdx.y * 128;
  const int ks = blockIdx.z;
  const int tid = threadIdx.x;
  const int lane = tid & 63;
  const int w = tid >> 6;
  const int wm = w >> 1, wn = w & 1;

  const int r_in_chunk = lane >> 2;
  const int kpart = (lane & 3) * 8;

  const unsigned short* Abase = act + (size_t)row0 * EI_;
  const unsigned short* Bbase = w2t + (size_t)col0 * EI_;

  f32x4 acc[4][4] = {};

  const int lrow = lane & 15;
  const int lk = (lane >> 4) * 8;

  const int kbeg = ks * KLEN;
  for (int k0 = kbeg; k0 < kbeg + KLEN; k0 += 32) {
    for (int i = 0; i < 2; ++i) {
      int c = w * 2 + i;
      int row = c * 16 + r_in_chunk;
      gload_lds16(Abase + (size_t)row * EI_ + k0 + kpart, &Asm[c * 512]);
      gload_lds16(Bbase + (size_t)row * EI_ + k0 + kpart, &Bsm[c * 512]);
    }
    __syncthreads();
    bf16x8 af[4], bf[4];
    for (int m = 0; m < 4; ++m)
      af[m] = *reinterpret_cast<const bf16x8*>(&Asm[(wm * 64 + m * 16 + lrow) * 32 + lk]);
    for (int n = 0; n < 4; ++n)
      bf[n] = *reinterpret_cast<const bf16x8*>(&Bsm[(wn * 64 + n * 16 + lrow) * 32 + lk]);
    for (int m = 0; m < 4; ++m)
      for (int n = 0; n < 4; ++n)
        acc[m][n] = __builtin_amdgcn_mfma_f32_16x16x32_bf16(af[m], bf[n], acc[m][n], 0, 0, 0);
    __syncthreads();
  }

  float* dbase = dout + (size_t)ks * T_ * H_;
  const int crow = (lane >> 4) * 4;
  const int ccol = lane & 15;
  for (int m = 0; m < 4; ++m)
    for (int n = 0; n < 4; ++n)
      for (int r = 0; r < 4; ++r) {
        int rl = wm * 64 + m * 16 + crow + r;
        int cl = wn * 64 + n * 16 + ccol;
        dbase[(size_t)(row0 + rl) * H_ + col0 + cl] = acc[m][n][r];
      }
}

// ---------------- Reduce split-K partials ----------------
__global__ void reduce_kernel(const float* __restrict__ dout,
                              float* __restrict__ out) {
  int idx = blockIdx.x * blockDim.x + threadIdx.x;
  const float4* a = reinterpret_cast<const float4*>(dout);
  const float4* b = a + (size_t)T_ * H_ / 4;
  const float4* c = b + (size_t)T_ * H_ / 4;
  float4 va = a[idx], vb = b[idx], vc = c[idx];
  float4 o;
  o.x = va.x + vb.x + vc.x;
  o.y = va.y + vb.y + vc.y;
  o.z = va.z + vb.z + vc.z;
  o.w = va.w + vb.w + vc.w;
  reinterpret_cast<float4*>(out)[idx] = o;
}

extern "C" void kernel_launch(void* const* d_in, const int* in_sizes, int n_in,
                              void* d_out, int out_size, void* d_ws, size_t ws_size,
                              hipStream_t stream) {
  const float* x      = (const float*)d_in[0];
  const float* gate_w = (const float*)d_in[1];
  const float* w1     = (const float*)d_in[2];
  const float* w3     = (const float*)d_in[3];
  const float* w2     = (const float*)d_in[4];
  float* out = (float*)d_out;

  // workspace layout (all 16B-aligned); total ~176.3 MB
  char* ws = (char*)d_ws;
  float* dense_w      = (float*)ws;                               // T*E*4      = 256KB
  unsigned short* xb  = (unsigned short*)(ws + 262144);           // T*H*2      = 8MB
  unsigned short* w1t = xb  + (size_t)T_ * H_;                    // E*I*H*2    = 24MB
  unsigned short* w3t = w1t + (size_t)E_ * I_ * H_;               // 24MB
  unsigned short* w2t = w3t + (size_t)E_ * I_ * H_;               // H*EI*2     = 24MB
  unsigned short* act = w2t + (size_t)H_ * EI_;                   // T*EI*2     = 96MB
  // dout aliases w1t+w3t (dead after moe_up): KSPLIT*T*H*4 = 48MB
  float* dout = (float*)w1t;

  router_kernel<<<T_, 64, 0, stream>>>(x, gate_w, dense_w);
  cast_x_kernel<<<(T_ * H_ / 4) / 256, 256, 0, stream>>>(x, xb);
  transpose_w13_kernel<<<dim3(I_ / 64, H_ / 64, 32), 256, 0, stream>>>(w1, w3, w1t, w3t);
  transpose_w2_kernel<<<dim3(H_ / 64, I_ / 64, E_), 256, 0, stream>>>(w2, w2t);
  moe_up_kernel<<<dim3(T_ / 128, I_ / 64, E_), 256, 0, stream>>>(xb, w1t, w3t, dense_w, act);
  moe_down_kernel<<<dim3(T_ / 128, H_ / 128, KSPLIT), 256, 0, stream>>>(act, w2t, dout);
  reduce_kernel<<<(T_ * H_ / 4) / 256, 256, 0, stream>>>(dout, out);
}